// Round 14
// baseline (517.787 us; speedup 1.0000x reference)
//
#include <hip/hip_runtime.h>
#include <hip/hip_bf16.h>

// PatchGINEncoder on MI355X.
// R1: int inputs arrive as int32 (ei[e]=src, ei[E+e]=dst; batch int32[N]).
// R2: sorted-batch bounds; fused MLP; wide aggregate.
// R3: dst-range-sliced count/scatter (fixed 106MB random write-back).
// R4 (FAILED): feature paneling -> 2x line over-fetch. Reverted.
// R5: aggregate fused into MLP (k_layer); gather straight into MFMA LDS.
// R6: pool re-parallelized over node chunks (105us -> ~12us).
// R7 (FAILED): single-block scan = 232us @ 0.15% occupancy.
// R8: two-level scan restored. (580us)
// R9 (FAILED, CONFLATED): unsliced count (the real regression) + 8-edge unroll.
// R10: int4 edge reads (neutral).
// R11: CSR -> fixed buckets col[node][64]; scatter merged into k_setup. (505us)
// R12 (FAILED): per-bucket sort — FETCH unchanged. Kept NSLICE=8.
// R13: sort reverted. (490us) k_layer: FETCH 190MB (structural floor ~205MB),
//     but VALUBusy 23% / Occ 33% => possibly miss-LATENCY bound, not rate.
// R14: single-variable retry of 8-deep gather (R9's good half). Occupancy
//     math: grid gives ~6.1 blocks/CU, so VGPR 52->~84 (9->6 waves/SIMD
//     capacity) doesn't bind; per-lane MLP doubles. If layer unchanged =>
//     L3 service-rate ceiling confirmed, gather is at roofline.

#define GDEPTH 3
#define CAP 64

typedef __bf16 bf16x8 __attribute__((ext_vector_type(8)));
typedef float  f32x4  __attribute__((ext_vector_type(4)));
typedef __hip_bfloat16  bf16;
typedef __hip_bfloat162 bf162;

#define CSR_CH 8192
#define NSLICE 8
#define NSLICE_LOG 3

// ------- fused setup: prep | convert x | graph bounds | bucket scatter -------
__global__ void k_setup(const float* __restrict__ W1s, const float* __restrict__ W2s,
                        const float* __restrict__ b1s, const float* __restrict__ bng,
                        const float* __restrict__ bnb, const float* __restrict__ bnm,
                        const float* __restrict__ bnv,
                        bf16* __restrict__ Wp1, bf16* __restrict__ Wp2,
                        float* __restrict__ sArr, float* __restrict__ tArr,
                        const float4* __restrict__ x4, bf162* __restrict__ h,
                        const int* __restrict__ batch, int* __restrict__ gp,
                        const int* __restrict__ ei, int* __restrict__ fill,
                        int* __restrict__ col,
                        int N, int E, int G, int BCONV, int BGB) {
    int bid = blockIdx.x;
    int tid = threadIdx.x;
    if (bid < 384) {
        // ---- weight prep: pack W into B-frag order, fold BN ----
        int idx = bid * 256 + tid;                 // [0, 6*16384)
        int l   = idx / 32768;
        int rem = idx - l * 32768;
        int w   = rem >> 14;
        int p   = rem & 16383;
        int j = p & 7, n = (p >> 3) & 127, tq = p >> 10;
        int quad = tq & 3, kk = tq >> 2;
        int k = kk * 32 + quad * 8 + j;
        const float* W = w ? W2s : W1s;
        bf16* Wp = w ? Wp2 : Wp1;
        Wp[l * 16384 + p] = __float2bfloat16(W[l * 16384 + k * 128 + n]);
        if (idx < GDEPTH * 128) {
            int ll = idx >> 7, c = idx & 127;
            float inv = rsqrtf(bnv[ll * 128 + c] + 1e-5f);
            float s = inv * bng[ll * 128 + c];
            sArr[idx] = s;
            tArr[idx] = (b1s[ll * 128 + c] - bnm[ll * 128 + c]) * s + bnb[ll * 128 + c];
        }
        return;
    }
    bid -= 384;
    if (bid < BCONV) {
        // ---- x -> bf16 ----
        int i = bid * 256 + tid;
        int n4 = N * 32;
        if (i < n4) {
            float4 v = x4[i];
            bf162 a, b;
            a.x = __float2bfloat16(v.x); a.y = __float2bfloat16(v.y);
            b.x = __float2bfloat16(v.z); b.y = __float2bfloat16(v.w);
            h[2 * i] = a; h[2 * i + 1] = b;
        }
        return;
    }
    bid -= BCONV;
    if (bid < BGB) {
        // ---- graph bounds from sorted batch ----
        int i = bid * 256 + tid;
        if (i < N) {
            int b = batch[i];
            if (i == 0) {
                for (int g = 0; g <= b; ++g) gp[g] = 0;
            } else {
                int pb = batch[i - 1];
                if (pb != b) for (int g = pb + 1; g <= b; ++g) gp[g] = i;
            }
            if (i == N - 1) {
                for (int g = b + 1; g <= G; ++g) gp[g] = N;
            }
        }
        return;
    }
    bid -= BGB;
    {
        // ---- sliced bucket scatter (atomic/write locality), int4 edge reads ----
        int s = bid & (NSLICE - 1);
        int chunk = bid >> NSLICE_LOG;
        int lo = (int)((long long)s * N / NSLICE);
        int hi = (int)((long long)(s + 1) * N / NSLICE);
        int baseq = chunk * (CSR_CH / 4);
        const int4* d4p = (const int4*)(ei + E);
        const int4* s4p = (const int4*)ei;
        #pragma unroll
        for (int i = 0; i < CSR_CH / 1024; ++i) {
            int q = baseq + i * 256 + tid;
            int e0 = q * 4;
            if (e0 + 3 < E) {
                int4 d4 = d4p[q];
                if ((d4.x >= lo && d4.x < hi) || (d4.y >= lo && d4.y < hi) ||
                    (d4.z >= lo && d4.z < hi) || (d4.w >= lo && d4.w < hi)) {
                    int4 s4 = s4p[q];
                    if (d4.x >= lo && d4.x < hi) { int p = atomicAdd(&fill[d4.x], 1); if (p < CAP) col[(size_t)d4.x * CAP + p] = s4.x; }
                    if (d4.y >= lo && d4.y < hi) { int p = atomicAdd(&fill[d4.y], 1); if (p < CAP) col[(size_t)d4.y * CAP + p] = s4.y; }
                    if (d4.z >= lo && d4.z < hi) { int p = atomicAdd(&fill[d4.z], 1); if (p < CAP) col[(size_t)d4.z * CAP + p] = s4.z; }
                    if (d4.w >= lo && d4.w < hi) { int p = atomicAdd(&fill[d4.w], 1); if (p < CAP) col[(size_t)d4.w * CAP + p] = s4.w; }
                }
            } else if (e0 < E) {
                for (int e = e0; e < E; ++e) {
                    int d = ei[E + e];
                    if (d >= lo && d < hi) {
                        int p = atomicAdd(&fill[d], 1);
                        if (p < CAP) col[(size_t)d * CAP + p] = ei[e];
                    }
                }
            }
        }
    }
}

// -------- fused layer: z = h + Ah (bucket gather) -> relu(BN(zW1+b1))W2+b2, relu --
__global__ __launch_bounds__(256) void k_layer(const bf16* __restrict__ h,
                                               const int* __restrict__ deg,
                                               const int* __restrict__ col,
                                               const bf16* __restrict__ Bp1,
                                               const bf16* __restrict__ Bp2,
                                               const float* __restrict__ sv,
                                               const float* __restrict__ tv,
                                               const float* __restrict__ b2,
                                               bf16* __restrict__ Out, int M) {
    __shared__ __align__(16) bf16 As[64 * 136];   // +8 pad
    const int tid = threadIdx.x;
    const int m0 = blockIdx.x * 64;
    const int grp = tid >> 4, c = tid & 15;
    const bf16x8* h8 = (const bf16x8*)h;           // row j chunk c at h8[j*16+c]

    #pragma unroll
    for (int it = 0; it < 4; ++it) {
        int row = grp * 4 + it;
        int node = m0 + row;
        float acc[8];
        if (node < M) {
            bf16x8 self = h8[(size_t)node * 16 + c];
            #pragma unroll
            for (int k = 0; k < 8; ++k) acc[k] = (float)self[k];
            int d = deg[node]; if (d > CAP) d = CAP;
            const int* cb = col + (size_t)node * CAP;
            int e = 0;
            // 8 gathers in flight per lane (miss-latency MLP)
            for (; e + 7 < d; e += 8) {
                int j0 = cb[e],     j1 = cb[e + 1], j2 = cb[e + 2], j3 = cb[e + 3];
                int j4 = cb[e + 4], j5 = cb[e + 5], j6 = cb[e + 6], j7 = cb[e + 7];
                bf16x8 v0 = h8[(size_t)j0 * 16 + c];
                bf16x8 v1 = h8[(size_t)j1 * 16 + c];
                bf16x8 v2 = h8[(size_t)j2 * 16 + c];
                bf16x8 v3 = h8[(size_t)j3 * 16 + c];
                bf16x8 v4 = h8[(size_t)j4 * 16 + c];
                bf16x8 v5 = h8[(size_t)j5 * 16 + c];
                bf16x8 v6 = h8[(size_t)j6 * 16 + c];
                bf16x8 v7 = h8[(size_t)j7 * 16 + c];
                #pragma unroll
                for (int k = 0; k < 8; ++k)
                    acc[k] += (((float)v0[k] + (float)v1[k]) + ((float)v2[k] + (float)v3[k]))
                            + (((float)v4[k] + (float)v5[k]) + ((float)v6[k] + (float)v7[k]));
            }
            for (; e + 3 < d; e += 4) {
                int j0 = cb[e], j1 = cb[e + 1], j2 = cb[e + 2], j3 = cb[e + 3];
                bf16x8 v0 = h8[(size_t)j0 * 16 + c];
                bf16x8 v1 = h8[(size_t)j1 * 16 + c];
                bf16x8 v2 = h8[(size_t)j2 * 16 + c];
                bf16x8 v3 = h8[(size_t)j3 * 16 + c];
                #pragma unroll
                for (int k = 0; k < 8; ++k)
                    acc[k] += ((float)v0[k] + (float)v1[k]) + ((float)v2[k] + (float)v3[k]);
            }
            for (; e < d; ++e) {
                bf16x8 v = h8[(size_t)cb[e] * 16 + c];
                #pragma unroll
                for (int k = 0; k < 8; ++k) acc[k] += (float)v[k];
            }
        } else {
            #pragma unroll
            for (int k = 0; k < 8; ++k) acc[k] = 0.f;
        }
        bf16x8 r;
        #pragma unroll
        for (int k = 0; k < 8; ++k) {
            __hip_bfloat16 t = __float2bfloat16(acc[k]);
            r[k] = *(__bf16*)&t;
        }
        *(bf16x8*)(As + row * 136 + c * 8) = r;
    }
    __syncthreads();

    const int lane = tid & 63;
    const int wid = tid >> 6;
    const int wm = wid & 1, wn = wid >> 1;
    const int l15 = lane & 15, quad = lane >> 4;

    f32x4 acc[2][4];
    #pragma unroll
    for (int i = 0; i < 2; ++i)
        #pragma unroll
        for (int j = 0; j < 4; ++j) acc[i][j] = (f32x4){0.f, 0.f, 0.f, 0.f};
    #pragma unroll
    for (int kk = 0; kk < 4; ++kk) {
        bf16x8 a[2], b[4];
        #pragma unroll
        for (int tn = 0; tn < 4; ++tn)
            b[tn] = *(const bf16x8*)(Bp1 + ((kk * 4 + quad) * 128 + wn * 64 + tn * 16 + l15) * 8);
        #pragma unroll
        for (int tm = 0; tm < 2; ++tm)
            a[tm] = *(const bf16x8*)(As + (wm * 32 + tm * 16 + l15) * 136 + kk * 32 + quad * 8);
        #pragma unroll
        for (int tm = 0; tm < 2; ++tm)
            #pragma unroll
            for (int tn = 0; tn < 4; ++tn)
                acc[tm][tn] = __builtin_amdgcn_mfma_f32_16x16x32_bf16(a[tm], b[tn], acc[tm][tn], 0, 0, 0);
    }
    __syncthreads();                               // all GEMM1 A-reads done
    // epilogue1: y = relu(acc*s + t) -> LDS (C/D: col=lane&15, row=quad*4+reg)
    #pragma unroll
    for (int tn = 0; tn < 4; ++tn) {
        int gc = wn * 64 + tn * 16 + l15;
        float scale = sv[gc], shift = tv[gc];
        #pragma unroll
        for (int tm = 0; tm < 2; ++tm)
            #pragma unroll
            for (int r = 0; r < 4; ++r) {
                float v = fmaxf(acc[tm][tn][r] * scale + shift, 0.f);
                int row = wm * 32 + tm * 16 + quad * 4 + r;
                __hip_bfloat16 t = __float2bfloat16(v);
                As[row * 136 + gc] = *(bf16*)&t;
            }
    }
    __syncthreads();                               // y fully in LDS
    #pragma unroll
    for (int i = 0; i < 2; ++i)
        #pragma unroll
        for (int j = 0; j < 4; ++j) acc[i][j] = (f32x4){0.f, 0.f, 0.f, 0.f};
    #pragma unroll
    for (int kk = 0; kk < 4; ++kk) {
        bf16x8 a[2], b[4];
        #pragma unroll
        for (int tn = 0; tn < 4; ++tn)
            b[tn] = *(const bf16x8*)(Bp2 + ((kk * 4 + quad) * 128 + wn * 64 + tn * 16 + l15) * 8);
        #pragma unroll
        for (int tm = 0; tm < 2; ++tm)
            a[tm] = *(const bf16x8*)(As + (wm * 32 + tm * 16 + l15) * 136 + kk * 32 + quad * 8);
        #pragma unroll
        for (int tm = 0; tm < 2; ++tm)
            #pragma unroll
            for (int tn = 0; tn < 4; ++tn)
                acc[tm][tn] = __builtin_amdgcn_mfma_f32_16x16x32_bf16(a[tm], b[tn], acc[tm][tn], 0, 0, 0);
    }
    // epilogue2: h_next = relu(acc + b2) -> global (different buffer)
    #pragma unroll
    for (int tn = 0; tn < 4; ++tn) {
        int gc = wn * 64 + tn * 16 + l15;
        float shift = b2[gc];
        #pragma unroll
        for (int tm = 0; tm < 2; ++tm)
            #pragma unroll
            for (int r = 0; r < 4; ++r) {
                int gr = m0 + wm * 32 + tm * 16 + quad * 4 + r;
                if (gr < M) {
                    float v = fmaxf(acc[tm][tn][r] + shift, 0.f);
                    Out[(size_t)gr * 128 + gc] = __float2bfloat16(v);
                }
            }
    }
}

// ---------------- pooling: node-chunk parallel, atomic flush at boundaries ------
#define PCH 128
__global__ void k_pool(const bf16* __restrict__ h, const int* __restrict__ batch,
                       float* __restrict__ hga, int N) {
    int base = blockIdx.x * PCH;
    if (base >= N) return;
    int t = threadIdx.x;
    int end = base + PCH; if (end > N) end = N;
    int gcur = batch[base];
    float acc = 0.f;
    for (int i = base; i < end; ++i) {
        int g = batch[i];
        if (g != gcur) {
            atomicAdd(&hga[gcur * 128 + t], acc);
            acc = 0.f; gcur = g;
        }
        acc += __bfloat162float(h[(size_t)i * 128 + t]);
    }
    atomicAdd(&hga[gcur * 128 + t], acc);
}

// ---------------- mean + projection + LayerNorm (fp32) ----------------
__global__ void k_proj_ln(const float* __restrict__ hga, const int* __restrict__ gp,
                          const float* __restrict__ Wp,
                          const float* __restrict__ bp, const float* __restrict__ lng,
                          const float* __restrict__ lnb, float* __restrict__ out) {
    __shared__ float row[128];
    __shared__ float red[128];
    int g = blockIdx.x, t = threadIdx.x;
    int cntn = gp[g + 1] - gp[g];
    float inv = 1.0f / (float)(cntn < 1 ? 1 : cntn);
    row[t] = hga[g * 128 + t] * inv;
    __syncthreads();
    float p = bp[t];
    #pragma unroll 8
    for (int k = 0; k < 128; ++k) p += row[k] * Wp[k * 128 + t];
    red[t] = p; __syncthreads();
    for (int o = 64; o > 0; o >>= 1) { if (t < o) red[t] += red[t + o]; __syncthreads(); }
    float mu = red[0] * (1.0f / 128.0f);
    __syncthreads();
    float d = p - mu;
    red[t] = d * d; __syncthreads();
    for (int o = 64; o > 0; o >>= 1) { if (t < o) red[t] += red[t + o]; __syncthreads(); }
    float var = red[0] * (1.0f / 128.0f);
    out[g * 128 + t] = d * rsqrtf(var + 1e-5f) * lng[t] + lnb[t];
}

extern "C" void kernel_launch(void* const* d_in, const int* in_sizes, int n_in,
                              void* d_out, int out_size, void* d_ws, size_t ws_size,
                              hipStream_t stream) {
    const float* x   = (const float*)d_in[0];
    const int*   ei  = (const int*)d_in[1];    // int32: [src(E), dst(E)]
    const int*   bat = (const int*)d_in[2];    // int32, sorted
    const float* W1s = (const float*)d_in[3];
    const float* b1s = (const float*)d_in[4];
    const float* bng = (const float*)d_in[5];
    const float* bnb = (const float*)d_in[6];
    const float* bnm = (const float*)d_in[7];
    const float* bnv = (const float*)d_in[8];
    const float* W2s = (const float*)d_in[9];
    const float* b2s = (const float*)d_in[10];
    const float* Wp  = (const float*)d_in[11];
    const float* bp  = (const float*)d_in[12];
    const float* lng = (const float*)d_in[13];
    const float* lnb = (const float*)d_in[14];
    const int E = in_sizes[1] / 2;
    const int N = in_sizes[2];
    const int G = out_size / 128;

    char* w = (char*)d_ws;
    size_t off = 0;
    auto alloc = [&](size_t b) { char* p = w + off; off += (b + 255) & ~(size_t)255; return p; };
    bf16* buf_a = (bf16*)alloc((size_t)N * 128 * 2);
    bf16* buf_b = (bf16*)alloc((size_t)N * 128 * 2);
    int* col   = (int*)alloc(((size_t)N * CAP + 256) * 4);
    int* fill  = (int*)alloc((size_t)N * 4);
    int* gp    = (int*)alloc(2048);
    bf16* Wp1  = (bf16*)alloc((size_t)GDEPTH * 16384 * 2);
    bf16* Wp2  = (bf16*)alloc((size_t)GDEPTH * 16384 * 2);
    float* sA  = (float*)alloc((size_t)GDEPTH * 128 * 4);
    float* tA  = (float*)alloc((size_t)GDEPTH * 128 * 4);
    float* hga = (float*)alloc((size_t)G * 128 * 4);

    hipMemsetAsync(fill, 0, (size_t)N * 4, stream);
    hipMemsetAsync(hga, 0, (size_t)G * 128 * 4, stream);

    const int BCONV = (N * 32 + 255) / 256;
    const int BGB   = (N + 255) / 256;
    const int BCSR  = ((E + CSR_CH - 1) / CSR_CH) * NSLICE;   // sliced bucket scatter
    k_setup<<<384 + BCONV + BGB + BCSR, 256, 0, stream>>>(
        W1s, W2s, b1s, bng, bnb, bnm, bnv, Wp1, Wp2, sA, tA,
        (const float4*)x, (bf162*)buf_a, bat, gp, ei, fill, col, N, E, G, BCONV, BGB);

    const bf16* hcur = buf_a;
    bf16* hnext = buf_b;
    for (int l = 0; l < GDEPTH; ++l) {
        k_layer<<<(N + 63) / 64, 256, 0, stream>>>(hcur, fill, col,
                                                   Wp1 + (size_t)l * 16384,
                                                   Wp2 + (size_t)l * 16384,
                                                   sA + l * 128, tA + l * 128,
                                                   b2s + l * 128, hnext, N);
        bf16* tmp = hnext; hnext = (bf16*)hcur; hcur = tmp;
    }
    k_pool<<<(N + PCH - 1) / PCH, 128, 0, stream>>>(hcur, bat, hga, N);
    k_proj_ln<<<G, 128, 0, stream>>>(hga, gp, Wp, bp, lng, lnb, (float*)d_out);
}

// Round 15
// 481.925 us; speedup vs baseline: 1.0744x; 1.0744x over previous
//
#include <hip/hip_runtime.h>
#include <hip/hip_bf16.h>

// PatchGINEncoder on MI355X.
// R1: int inputs arrive as int32 (ei[e]=src, ei[E+e]=dst; batch int32[N]).
// R2: sorted-batch bounds; fused MLP; wide aggregate.
// R3: dst-range-sliced count/scatter (fixed 106MB random write-back).
// R4 (FAILED): feature paneling -> 2x line over-fetch. Reverted.
// R5: aggregate fused into MLP (k_layer); gather straight into MFMA LDS.
// R6: pool re-parallelized over node chunks (105us -> ~12us).
// R7 (FAILED): single-block scan = 232us @ 0.15% occupancy.
// R8: two-level scan restored. (580us)
// R9 (FAILED, CONFLATED): unsliced count + 8-edge unroll.
// R10: int4 edge reads (neutral).
// R11: CSR -> fixed buckets col[node][64]; scatter merged into k_setup. (505us)
// R12 (FAILED): per-bucket sort — FETCH unchanged. Kept NSLICE=8.
// R13: sort reverted. (490us)
// R14 (FAILED, informative): 8-deep gather: VGPR 52->68, occ 33->26%, layer
//     87->104us, time rose ~proportional to lost waves, FETCH unchanged.
//     => gather throughput ∝ RESIDENT WAVES (TLP-limited latency service,
//     not rate-capped, not per-lane-depth-limited).
// R15: 32-row tiles (grid 3125 = 12.2 blocks/CU vs 6.1; static occupancy
//     76%->100% + block replacement). Gather loop = proven 4-deep form.
//     MFMA/row unchanged; acc regs halve. N = 32*3125 exactly.

#define GDEPTH 3
#define CAP 64

typedef __bf16 bf16x8 __attribute__((ext_vector_type(8)));
typedef float  f32x4  __attribute__((ext_vector_type(4)));
typedef __hip_bfloat16  bf16;
typedef __hip_bfloat162 bf162;

#define CSR_CH 8192
#define NSLICE 8
#define NSLICE_LOG 3

// ------- fused setup: prep | convert x | graph bounds | bucket scatter -------
__global__ void k_setup(const float* __restrict__ W1s, const float* __restrict__ W2s,
                        const float* __restrict__ b1s, const float* __restrict__ bng,
                        const float* __restrict__ bnb, const float* __restrict__ bnm,
                        const float* __restrict__ bnv,
                        bf16* __restrict__ Wp1, bf16* __restrict__ Wp2,
                        float* __restrict__ sArr, float* __restrict__ tArr,
                        const float4* __restrict__ x4, bf162* __restrict__ h,
                        const int* __restrict__ batch, int* __restrict__ gp,
                        const int* __restrict__ ei, int* __restrict__ fill,
                        int* __restrict__ col,
                        int N, int E, int G, int BCONV, int BGB) {
    int bid = blockIdx.x;
    int tid = threadIdx.x;
    if (bid < 384) {
        // ---- weight prep: pack W into B-frag order, fold BN ----
        int idx = bid * 256 + tid;                 // [0, 6*16384)
        int l   = idx / 32768;
        int rem = idx - l * 32768;
        int w   = rem >> 14;
        int p   = rem & 16383;
        int j = p & 7, n = (p >> 3) & 127, tq = p >> 10;
        int quad = tq & 3, kk = tq >> 2;
        int k = kk * 32 + quad * 8 + j;
        const float* W = w ? W2s : W1s;
        bf16* Wp = w ? Wp2 : Wp1;
        Wp[l * 16384 + p] = __float2bfloat16(W[l * 16384 + k * 128 + n]);
        if (idx < GDEPTH * 128) {
            int ll = idx >> 7, c = idx & 127;
            float inv = rsqrtf(bnv[ll * 128 + c] + 1e-5f);
            float s = inv * bng[ll * 128 + c];
            sArr[idx] = s;
            tArr[idx] = (b1s[ll * 128 + c] - bnm[ll * 128 + c]) * s + bnb[ll * 128 + c];
        }
        return;
    }
    bid -= 384;
    if (bid < BCONV) {
        // ---- x -> bf16 ----
        int i = bid * 256 + tid;
        int n4 = N * 32;
        if (i < n4) {
            float4 v = x4[i];
            bf162 a, b;
            a.x = __float2bfloat16(v.x); a.y = __float2bfloat16(v.y);
            b.x = __float2bfloat16(v.z); b.y = __float2bfloat16(v.w);
            h[2 * i] = a; h[2 * i + 1] = b;
        }
        return;
    }
    bid -= BCONV;
    if (bid < BGB) {
        // ---- graph bounds from sorted batch ----
        int i = bid * 256 + tid;
        if (i < N) {
            int b = batch[i];
            if (i == 0) {
                for (int g = 0; g <= b; ++g) gp[g] = 0;
            } else {
                int pb = batch[i - 1];
                if (pb != b) for (int g = pb + 1; g <= b; ++g) gp[g] = i;
            }
            if (i == N - 1) {
                for (int g = b + 1; g <= G; ++g) gp[g] = N;
            }
        }
        return;
    }
    bid -= BGB;
    {
        // ---- sliced bucket scatter (atomic/write locality), int4 edge reads ----
        int s = bid & (NSLICE - 1);
        int chunk = bid >> NSLICE_LOG;
        int lo = (int)((long long)s * N / NSLICE);
        int hi = (int)((long long)(s + 1) * N / NSLICE);
        int baseq = chunk * (CSR_CH / 4);
        const int4* d4p = (const int4*)(ei + E);
        const int4* s4p = (const int4*)ei;
        #pragma unroll
        for (int i = 0; i < CSR_CH / 1024; ++i) {
            int q = baseq + i * 256 + tid;
            int e0 = q * 4;
            if (e0 + 3 < E) {
                int4 d4 = d4p[q];
                if ((d4.x >= lo && d4.x < hi) || (d4.y >= lo && d4.y < hi) ||
                    (d4.z >= lo && d4.z < hi) || (d4.w >= lo && d4.w < hi)) {
                    int4 s4 = s4p[q];
                    if (d4.x >= lo && d4.x < hi) { int p = atomicAdd(&fill[d4.x], 1); if (p < CAP) col[(size_t)d4.x * CAP + p] = s4.x; }
                    if (d4.y >= lo && d4.y < hi) { int p = atomicAdd(&fill[d4.y], 1); if (p < CAP) col[(size_t)d4.y * CAP + p] = s4.y; }
                    if (d4.z >= lo && d4.z < hi) { int p = atomicAdd(&fill[d4.z], 1); if (p < CAP) col[(size_t)d4.z * CAP + p] = s4.z; }
                    if (d4.w >= lo && d4.w < hi) { int p = atomicAdd(&fill[d4.w], 1); if (p < CAP) col[(size_t)d4.w * CAP + p] = s4.w; }
                }
            } else if (e0 < E) {
                for (int e = e0; e < E; ++e) {
                    int d = ei[E + e];
                    if (d >= lo && d < hi) {
                        int p = atomicAdd(&fill[d], 1);
                        if (p < CAP) col[(size_t)d * CAP + p] = ei[e];
                    }
                }
            }
        }
    }
}

// -------- fused layer, 32-row tile: z = h + Ah -> relu(BN(zW1+b1))W2+b2, relu ----
__global__ __launch_bounds__(256) void k_layer(const bf16* __restrict__ h,
                                               const int* __restrict__ deg,
                                               const int* __restrict__ col,
                                               const bf16* __restrict__ Bp1,
                                               const bf16* __restrict__ Bp2,
                                               const float* __restrict__ sv,
                                               const float* __restrict__ tv,
                                               const float* __restrict__ b2,
                                               bf16* __restrict__ Out, int M) {
    __shared__ __align__(16) bf16 As[32 * 136];   // +8 pad
    const int tid = threadIdx.x;
    const int m0 = blockIdx.x * 32;
    const int grp = tid >> 4, c = tid & 15;
    const bf16x8* h8 = (const bf16x8*)h;           // row j chunk c at h8[j*16+c]

    #pragma unroll
    for (int it = 0; it < 2; ++it) {
        int row = grp * 2 + it;
        int node = m0 + row;
        float acc[8];
        if (node < M) {
            bf16x8 self = h8[(size_t)node * 16 + c];
            #pragma unroll
            for (int k = 0; k < 8; ++k) acc[k] = (float)self[k];
            int d = deg[node]; if (d > CAP) d = CAP;
            const int* cb = col + (size_t)node * CAP;
            int e = 0;
            for (; e + 3 < d; e += 4) {
                int j0 = cb[e], j1 = cb[e + 1], j2 = cb[e + 2], j3 = cb[e + 3];
                bf16x8 v0 = h8[(size_t)j0 * 16 + c];
                bf16x8 v1 = h8[(size_t)j1 * 16 + c];
                bf16x8 v2 = h8[(size_t)j2 * 16 + c];
                bf16x8 v3 = h8[(size_t)j3 * 16 + c];
                #pragma unroll
                for (int k = 0; k < 8; ++k)
                    acc[k] += ((float)v0[k] + (float)v1[k]) + ((float)v2[k] + (float)v3[k]);
            }
            for (; e < d; ++e) {
                bf16x8 v = h8[(size_t)cb[e] * 16 + c];
                #pragma unroll
                for (int k = 0; k < 8; ++k) acc[k] += (float)v[k];
            }
        } else {
            #pragma unroll
            for (int k = 0; k < 8; ++k) acc[k] = 0.f;
        }
        bf16x8 r;
        #pragma unroll
        for (int k = 0; k < 8; ++k) {
            __hip_bfloat16 t = __float2bfloat16(acc[k]);
            r[k] = *(__bf16*)&t;
        }
        *(bf16x8*)(As + row * 136 + c * 8) = r;
    }
    __syncthreads();

    const int lane = tid & 63;
    const int wid = tid >> 6;
    const int wm = wid & 1, wn = wid >> 1;     // wm: 16-row half; wn: 64-col half
    const int l15 = lane & 15, quad = lane >> 4;

    f32x4 acc[4];
    #pragma unroll
    for (int j = 0; j < 4; ++j) acc[j] = (f32x4){0.f, 0.f, 0.f, 0.f};
    #pragma unroll
    for (int kk = 0; kk < 4; ++kk) {
        bf16x8 a, b[4];
        #pragma unroll
        for (int tn = 0; tn < 4; ++tn)
            b[tn] = *(const bf16x8*)(Bp1 + ((kk * 4 + quad) * 128 + wn * 64 + tn * 16 + l15) * 8);
        a = *(const bf16x8*)(As + (wm * 16 + l15) * 136 + kk * 32 + quad * 8);
        #pragma unroll
        for (int tn = 0; tn < 4; ++tn)
            acc[tn] = __builtin_amdgcn_mfma_f32_16x16x32_bf16(a, b[tn], acc[tn], 0, 0, 0);
    }
    __syncthreads();                               // all GEMM1 A-reads done
    // epilogue1: y = relu(acc*s + t) -> LDS (C/D: col=lane&15, row=quad*4+reg)
    #pragma unroll
    for (int tn = 0; tn < 4; ++tn) {
        int gc = wn * 64 + tn * 16 + l15;
        float scale = sv[gc], shift = tv[gc];
        #pragma unroll
        for (int r = 0; r < 4; ++r) {
            float v = fmaxf(acc[tn][r] * scale + shift, 0.f);
            int row = wm * 16 + quad * 4 + r;
            __hip_bfloat16 t = __float2bfloat16(v);
            As[row * 136 + gc] = *(bf16*)&t;
        }
    }
    __syncthreads();                               // y fully in LDS
    #pragma unroll
    for (int j = 0; j < 4; ++j) acc[j] = (f32x4){0.f, 0.f, 0.f, 0.f};
    #pragma unroll
    for (int kk = 0; kk < 4; ++kk) {
        bf16x8 a, b[4];
        #pragma unroll
        for (int tn = 0; tn < 4; ++tn)
            b[tn] = *(const bf16x8*)(Bp2 + ((kk * 4 + quad) * 128 + wn * 64 + tn * 16 + l15) * 8);
        a = *(const bf16x8*)(As + (wm * 16 + l15) * 136 + kk * 32 + quad * 8);
        #pragma unroll
        for (int tn = 0; tn < 4; ++tn)
            acc[tn] = __builtin_amdgcn_mfma_f32_16x16x32_bf16(a, b[tn], acc[tn], 0, 0, 0);
    }
    // epilogue2: h_next = relu(acc + b2) -> global (different buffer)
    #pragma unroll
    for (int tn = 0; tn < 4; ++tn) {
        int gc = wn * 64 + tn * 16 + l15;
        float shift = b2[gc];
        #pragma unroll
        for (int r = 0; r < 4; ++r) {
            int gr = m0 + wm * 16 + quad * 4 + r;
            if (gr < M) {
                float v = fmaxf(acc[tn][r] + shift, 0.f);
                Out[(size_t)gr * 128 + gc] = __float2bfloat16(v);
            }
        }
    }
}

// ---------------- pooling: node-chunk parallel, atomic flush at boundaries ------
#define PCH 128
__global__ void k_pool(const bf16* __restrict__ h, const int* __restrict__ batch,
                       float* __restrict__ hga, int N) {
    int base = blockIdx.x * PCH;
    if (base >= N) return;
    int t = threadIdx.x;
    int end = base + PCH; if (end > N) end = N;
    int gcur = batch[base];
    float acc = 0.f;
    for (int i = base; i < end; ++i) {
        int g = batch[i];
        if (g != gcur) {
            atomicAdd(&hga[gcur * 128 + t], acc);
            acc = 0.f; gcur = g;
        }
        acc += __bfloat162float(h[(size_t)i * 128 + t]);
    }
    atomicAdd(&hga[gcur * 128 + t], acc);
}

// ---------------- mean + projection + LayerNorm (fp32) ----------------
__global__ void k_proj_ln(const float* __restrict__ hga, const int* __restrict__ gp,
                          const float* __restrict__ Wp,
                          const float* __restrict__ bp, const float* __restrict__ lng,
                          const float* __restrict__ lnb, float* __restrict__ out) {
    __shared__ float row[128];
    __shared__ float red[128];
    int g = blockIdx.x, t = threadIdx.x;
    int cntn = gp[g + 1] - gp[g];
    float inv = 1.0f / (float)(cntn < 1 ? 1 : cntn);
    row[t] = hga[g * 128 + t] * inv;
    __syncthreads();
    float p = bp[t];
    #pragma unroll 8
    for (int k = 0; k < 128; ++k) p += row[k] * Wp[k * 128 + t];
    red[t] = p; __syncthreads();
    for (int o = 64; o > 0; o >>= 1) { if (t < o) red[t] += red[t + o]; __syncthreads(); }
    float mu = red[0] * (1.0f / 128.0f);
    __syncthreads();
    float d = p - mu;
    red[t] = d * d; __syncthreads();
    for (int o = 64; o > 0; o >>= 1) { if (t < o) red[t] += red[t + o]; __syncthreads(); }
    float var = red[0] * (1.0f / 128.0f);
    out[g * 128 + t] = d * rsqrtf(var + 1e-5f) * lng[t] + lnb[t];
}

extern "C" void kernel_launch(void* const* d_in, const int* in_sizes, int n_in,
                              void* d_out, int out_size, void* d_ws, size_t ws_size,
                              hipStream_t stream) {
    const float* x   = (const float*)d_in[0];
    const int*   ei  = (const int*)d_in[1];    // int32: [src(E), dst(E)]
    const int*   bat = (const int*)d_in[2];    // int32, sorted
    const float* W1s = (const float*)d_in[3];
    const float* b1s = (const float*)d_in[4];
    const float* bng = (const float*)d_in[5];
    const float* bnb = (const float*)d_in[6];
    const float* bnm = (const float*)d_in[7];
    const float* bnv = (const float*)d_in[8];
    const float* W2s = (const float*)d_in[9];
    const float* b2s = (const float*)d_in[10];
    const float* Wp  = (const float*)d_in[11];
    const float* bp  = (const float*)d_in[12];
    const float* lng = (const float*)d_in[13];
    const float* lnb = (const float*)d_in[14];
    const int E = in_sizes[1] / 2;
    const int N = in_sizes[2];
    const int G = out_size / 128;

    char* w = (char*)d_ws;
    size_t off = 0;
    auto alloc = [&](size_t b) { char* p = w + off; off += (b + 255) & ~(size_t)255; return p; };
    bf16* buf_a = (bf16*)alloc((size_t)N * 128 * 2);
    bf16* buf_b = (bf16*)alloc((size_t)N * 128 * 2);
    int* col   = (int*)alloc(((size_t)N * CAP + 256) * 4);
    int* fill  = (int*)alloc((size_t)N * 4);
    int* gp    = (int*)alloc(2048);
    bf16* Wp1  = (bf16*)alloc((size_t)GDEPTH * 16384 * 2);
    bf16* Wp2  = (bf16*)alloc((size_t)GDEPTH * 16384 * 2);
    float* sA  = (float*)alloc((size_t)GDEPTH * 128 * 4);
    float* tA  = (float*)alloc((size_t)GDEPTH * 128 * 4);
    float* hga = (float*)alloc((size_t)G * 128 * 4);

    hipMemsetAsync(fill, 0, (size_t)N * 4, stream);
    hipMemsetAsync(hga, 0, (size_t)G * 128 * 4, stream);

    const int BCONV = (N * 32 + 255) / 256;
    const int BGB   = (N + 255) / 256;
    const int BCSR  = ((E + CSR_CH - 1) / CSR_CH) * NSLICE;   // sliced bucket scatter
    k_setup<<<384 + BCONV + BGB + BCSR, 256, 0, stream>>>(
        W1s, W2s, b1s, bng, bnb, bnm, bnv, Wp1, Wp2, sA, tA,
        (const float4*)x, (bf162*)buf_a, bat, gp, ei, fill, col, N, E, G, BCONV, BGB);

    const bf16* hcur = buf_a;
    bf16* hnext = buf_b;
    for (int l = 0; l < GDEPTH; ++l) {
        k_layer<<<(N + 31) / 32, 256, 0, stream>>>(hcur, fill, col,
                                                   Wp1 + (size_t)l * 16384,
                                                   Wp2 + (size_t)l * 16384,
                                                   sA + l * 128, tA + l * 128,
                                                   b2s + l * 128, hnext, N);
        bf16* tmp = hnext; hnext = (bf16*)hcur; hcur = tmp;
    }
    k_pool<<<(N + PCH - 1) / PCH, 128, 0, stream>>>(hcur, bat, hga, N);
    k_proj_ln<<<G, 128, 0, stream>>>(hga, gp, Wp, bp, lng, lnb, (float*)d_out);
}